// Round 1
// baseline (153.791 us; speedup 1.0000x reference)
//
#include <hip/hip_runtime.h>
#include <math.h>

#define N_WL 262144

#define T_REF 273.15
#define P_REF 101325.0
#define C_LIGHT 299792458.0
#define K_B 1.380649e-23
#define N_AVO 6.02214076e+23

__constant__ float c_nu0[10]  = {254.0f, 280.0f, 310.0f, 940.0f, 1130.0f, 1380.0f, 1400.0f, 1600.0f, 2000.0f, 2700.0f};
__constant__ float c_str[10]  = {1.15e-17f, 5e-18f, 1.9e-19f, 2.5e-23f, 8.2e-24f, 1.8e-22f, 3.5e-25f, 7.8e-26f, 4.2e-24f, 1.2e-24f};
__constant__ float c_wid[10]  = {2.0f, 3.0f, 2.5f, 3.0f, 2.5f, 4.0f, 3.0f, 2.5f, 4.0f, 3.5f};
__constant__ float c_texp[10] = {0.05f, 0.04f, 0.03f, 0.4f, 0.35f, 0.45f, 0.5f, 0.48f, 0.52f, 0.49f};
__constant__ float c_mass[10] = {48.f, 48.f, 48.f, 18.f, 18.f, 18.f, 44.f, 44.f, 44.f, 44.f};
__constant__ int   c_cidx[10] = {0, 0, 0, 1, 1, 1, 2, 2, 2, 2};

__device__ __forceinline__ float siluf(float x)     { return x / (1.0f + __expf(-x)); }
__device__ __forceinline__ float sigmoidf(float x)  { return 1.0f / (1.0f + __expf(-x)); }
__device__ __forceinline__ float softplusf(float x) { return fmaxf(x, 0.0f) + log1pf(expf(-fabsf(x))); }

// Humlicek-style branched w(x,y) matching the reference (real part only).
// At runtime physics (y = gamma_L/sigma ~ 1e5) branch 1 is always taken,
// uniformly across the wave -> no divergence, no transcendentals.
__device__ __forceinline__ float voigt_w(float x, float y) {
    float ax = fabsf(x);
    float s  = ax + y;
    if (s >= 15.0f) {
        float ur = y * y - x * x;
        float ui = -2.0f * x * y;
        float dr = 0.5f + ur, di = ui;
        float nr = 0.5641896f * y, ni = 0.5641896f * (-x);
        float den = dr * dr + di * di;
        return (nr * dr + ni * di) / den;
    } else if (ax >= 5.5f) {
        float ur = y * y - x * x;
        float ui = -2.0f * x * y;
        float pr = 1.410474f + 0.5641896f * ur;
        float pi_ = 0.5641896f * ui;
        float tr = y, ti = -x;
        float nr = tr * pr - ti * pi_;
        float ni = tr * pi_ + ti * pr;
        float u2r = ur * ur - ui * ui;
        float u2i = 2.0f * ur * ui;
        float dr = 0.75f + 3.0f * ur + u2r;
        float di = 3.0f * ui + u2i;
        float den = dr * dr + di * di;
        return (nr * dr + ni * di) / den;
    } else {
        float x2 = x * x;
        return expf(-x2) * cosf(2.0f * x * y) * 0.5641895835477563f
             + (2.0f * y / 3.14159265358979f) * sinf(x2) / (x2 + y * y + 1e-10f);
    }
}

// ---------------- single fused kernel ----------------
// Phase A: every block redundantly computes the scalar setup (line params,
//          continuum hidden layer h[32], mixing hidden state m2[64]).
//          Inputs are identical for all blocks -> identical results; the
//          ~20 KB of redundant weight reads are L2 hits after first touch.
//          This removes the setup-kernel launch + serial bubble (~8-12 us).
// Phase B: 4 wavelengths/thread, float4 loads (16 B/lane, 1 KiB/wave/instr).
//          256 blocks x 256 threads; BW-bound with deep independent-load ILP.
__global__ __launch_bounds__(256) void GasAbs_fused_kernel(
    const float* __restrict__ wl,
    const float* __restrict__ Tp, const float* __restrict__ Pp,
    const float* __restrict__ o3, const float* __restrict__ h2o, const float* __restrict__ co2,
    const float* __restrict__ mix_w1, const float* __restrict__ mix_b1,
    const float* __restrict__ mix_w2, const float* __restrict__ mix_b2,
    const float* __restrict__ mix_w3, const float* __restrict__ mix_b3,
    const float* __restrict__ cont_w1, const float* __restrict__ cont_b1,
    const float* __restrict__ cont_w2, const float* __restrict__ cont_b2,
    float* __restrict__ out)
{
    __shared__ float s_nu0[10], s_isig[10], s_y[10], s_scale[10];
    __shared__ float s_h[32];
    __shared__ float s_feat[10];
    __shared__ float s_m1[64];
    __shared__ float s_m2[64];

    const int t = threadIdx.x;

    // ---- Phase A: redundant per-block scalar setup ----
    if (t < 10) {
        const double T = (double)Tp[0];
        const double P = (double)Pp[0];
        const float cc3[3] = {o3[0], h2o[0], co2[0]};
        double nu0 = (double)c_nu0[t];
        double sT  = (double)c_str[t] * pow(T_REF / (T + 1e-12), (double)c_texp[t]);
        double gL  = (double)c_wid[t] * (P / (P_REF + 1e-12)) * sqrt(T_REF / (T + 1e-12));
        double gD  = nu0 / C_LIGHT * sqrt(2.0 * K_B * T * N_AVO / ((double)c_mass[t] + 1e-12));
        double sig = gD / (sqrt(2.0 * log(2.0)) + 1e-12);
        s_nu0[t]   = (float)nu0;
        s_isig[t]  = (float)(1.0 / (sig + 1e-12));
        s_y[t]     = (float)(gL / (sig + 1e-12));
        s_scale[t] = (float)((double)cc3[c_cidx[t]] * sT / (sig * sqrt(M_PI) + 1e-12));
    }
    if (t < 32) {
        const double T = (double)Tp[0];
        const double P = (double)Pp[0];
        float cf[5];
        cf[0] = (float)(T / (T_REF + 1e-12));
        cf[1] = (float)(P / (P_REF + 1e-12));
        cf[2] = h2o[0];
        cf[3] = 1.0f;
        cf[4] = 0.0f;
        float a = cont_b1[t];
        #pragma unroll
        for (int k = 0; k < 5; k++) a = fmaf(cf[k], cont_w1[k * 32 + t], a);
        s_h[t] = siluf(a);
    }
    __syncthreads();

    if (t < 8) {
        float w = wl[t];
        float c = cont_b2[t];
        #pragma unroll
        for (int j = 0; j < 32; j++) c = fmaf(s_h[j], cont_w2[(size_t)j * N_WL + t], c);
        float cross = softplusf(c);
        #pragma unroll
        for (int l = 0; l < 10; l++) {
            float x = (w - s_nu0[l]) * s_isig[l];
            cross = fmaf(s_scale[l], voigt_w(x, s_y[l]), cross);
        }
        s_feat[2 + t] = cross;
    }
    if (t == 0) {
        const double T = (double)Tp[0];
        const double P = (double)Pp[0];
        s_feat[0] = (float)(T / (T_REF + 1e-12));
        s_feat[1] = (float)(P / (P_REF + 1e-12));
    }
    __syncthreads();

    if (t < 64) {
        float a = mix_b1[t];
        #pragma unroll
        for (int k = 0; k < 10; k++) a = fmaf(s_feat[k], mix_w1[k * 64 + t], a);
        s_m1[t] = siluf(a);
    }
    __syncthreads();

    if (t < 64) {
        float a = mix_b2[t];
        #pragma unroll
        for (int k = 0; k < 64; k++) a = fmaf(s_m1[k], mix_w2[k * 64 + t], a);
        s_m2[t] = siluf(a);
    }
    __syncthreads();

    // ---- Phase B: stream 4 wavelengths per thread with float4 loads ----
    const int i0 = (blockIdx.x * 256 + t) * 4;

    const float4 w4 = *reinterpret_cast<const float4*>(wl + i0);

    // continuum: h . cont_w2[:, i] + b2
    float4 ac = *reinterpret_cast<const float4*>(cont_b2 + i0);
    #pragma unroll 16
    for (int j = 0; j < 32; j++) {
        const float hj = s_h[j];
        const float4 v = *reinterpret_cast<const float4*>(cont_w2 + (size_t)j * N_WL + i0);
        ac.x = fmaf(hj, v.x, ac.x);
        ac.y = fmaf(hj, v.y, ac.y);
        ac.z = fmaf(hj, v.z, ac.z);
        ac.w = fmaf(hj, v.w, ac.w);
    }

    float cr0 = softplusf(ac.x);
    float cr1 = softplusf(ac.y);
    float cr2 = softplusf(ac.z);
    float cr3 = softplusf(ac.w);

    #pragma unroll
    for (int l = 0; l < 10; l++) {
        const float nu0 = s_nu0[l], isig = s_isig[l], yy = s_y[l], sc = s_scale[l];
        cr0 = fmaf(sc, voigt_w((w4.x - nu0) * isig, yy), cr0);
        cr1 = fmaf(sc, voigt_w((w4.y - nu0) * isig, yy), cr1);
        cr2 = fmaf(sc, voigt_w((w4.z - nu0) * isig, yy), cr2);
        cr3 = fmaf(sc, voigt_w((w4.w - nu0) * isig, yy), cr3);
    }

    // mixing gate: sigmoid(m2 . mix_w3[:, i] + b3)
    float4 am = *reinterpret_cast<const float4*>(mix_b3 + i0);
    #pragma unroll 16
    for (int j = 0; j < 64; j++) {
        const float mj = s_m2[j];
        const float4 v = *reinterpret_cast<const float4*>(mix_w3 + (size_t)j * N_WL + i0);
        am.x = fmaf(mj, v.x, am.x);
        am.y = fmaf(mj, v.y, am.y);
        am.z = fmaf(mj, v.z, am.z);
        am.w = fmaf(mj, v.w, am.w);
    }

    float4 o;
    o.x = cr0 * (0.95f + 0.1f * sigmoidf(am.x));
    o.y = cr1 * (0.95f + 0.1f * sigmoidf(am.y));
    o.z = cr2 * (0.95f + 0.1f * sigmoidf(am.z));
    o.w = cr3 * (0.95f + 0.1f * sigmoidf(am.w));
    *reinterpret_cast<float4*>(out + i0) = o;
}

extern "C" void kernel_launch(void* const* d_in, const int* in_sizes, int n_in,
                              void* d_out, int out_size, void* d_ws, size_t ws_size,
                              hipStream_t stream) {
    const float* wl      = (const float*)d_in[0];
    const float* Tp      = (const float*)d_in[1];
    const float* Pp      = (const float*)d_in[2];
    const float* o3      = (const float*)d_in[3];
    const float* h2o     = (const float*)d_in[4];
    const float* co2     = (const float*)d_in[5];
    const float* mix_w1  = (const float*)d_in[6];
    const float* mix_b1  = (const float*)d_in[7];
    const float* mix_w2  = (const float*)d_in[8];
    const float* mix_b2  = (const float*)d_in[9];
    const float* mix_w3  = (const float*)d_in[10];
    const float* mix_b3  = (const float*)d_in[11];
    const float* cont_w1 = (const float*)d_in[12];
    const float* cont_b1 = (const float*)d_in[13];
    const float* cont_w2 = (const float*)d_in[14];
    const float* cont_b2 = (const float*)d_in[15];
    float* out = (float*)d_out;

    const int threads = 256;
    const int blocks  = N_WL / (threads * 4);  // 256 blocks, 4 wl/thread
    GasAbs_fused_kernel<<<blocks, threads, 0, stream>>>(
        wl, Tp, Pp, o3, h2o, co2,
        mix_w1, mix_b1, mix_w2, mix_b2, mix_w3, mix_b3,
        cont_w1, cont_b1, cont_w2, cont_b2, out);
}